// Round 9
// baseline (136.378 us; speedup 1.0000x reference)
//
#include <hip/hip_runtime.h>
#include <stdint.h>

#define WW 48
#define NQ 2304             // 48*48
#define NWT 144             // (bh, qt) tiles of 256 queries
#define SCL 0.51011868f     // 8^-0.5 * log2(e)  (folded so softmax = exp2)
#define SHIFT 17.312340491f // 12 * log2(e)      (fixed-shift softmax)
#define ACCF (NWT * 2304)   // 331776 floats: ACC[wt][9][256]
// ws layout (floats): [0,ACCF) ACC

typedef float v2f __attribute__((ext_vector_type(2)));

__device__ __forceinline__ v2f v2fma(v2f a, v2f b, v2f c) {
    return __builtin_elementwise_fma(a, b, c);   // -> v_pk_fma_f32
}

// ---------------------------------------------------------------------------
// attn: R28 = R27 slim body re-amortized j=2 -> j=4 (one wave covers 256
// queries' worth of logits per s_load window instead of 128).
// R27 counters (59.1us): FETCH 20.8->7.0MB (XCD-keying bx%8=h WORKED — K/V
// now L2-local), VALUBusy ~65% = ~38us VALU-occupancy (2cy x ~1100 instr x
// 18432 waves / 1024 SIMDs); residual ~21us = L2-hit s_load latency
// (~200cy) in the lgkmcnt path. Occupancy is an impotent lever (VALUBusy
// flat across occ 17->58%, R21/R24/R27) -> cut stall per-logit instead:
// K/V s_loads are shared across j, so j=4 halves wave count and total
// stall cycles at identical VALU work per logit. (R24 went 4->2 when
// stalls were 900cy HBM misses; R27's locality fix inverts that calculus.)
// __launch_bounds__(256,2): the j=4 slim s_load body measured exactly
// 84 VGPR spill-free at (256,2) in R23; (256,3)'s 85-cap is too tight.
// R20 lesson: no in-register K/V pipelining (spills). R25 lesson: no
// in-launch finish counters without agent-scope loads (norm stays separate).
// Diagnostic: WRITE_SIZE must stay 20.7MB — inflation = spill = revert.
// logit = q.k + q.rel_w[x2-x+47] + q.rel_h[y2-y+47]; p = exp2(logit-SHIFT)
// ---------------------------------------------------------------------------
__global__ __launch_bounds__(256, 2) void attn_kernel(const float* __restrict__ in,
                                                      const float* __restrict__ relw,
                                                      const float* __restrict__ relh,
                                                      float* __restrict__ ACC) {
    __shared__ float4 lds[1152];       // 18432 B: [0,190) relh during loop;
                                       // [0,1152) 2 merge regions after loop

    const int bx = blockIdx.x;
    // ---- XCD-keyed decode: bx%8 = h ----
    const int h = bx & 7;
    const int rest = bx >> 3;          // 0..287
    const int b = rest & 1;
    const int qg = rest >> 1;          // 0..143 = gg*9 + qt
    const int qt = qg % 9;
    const int gg = qg / 9;             // 0..15 (one 3-column chunk each)
    const int bh = b * 8 + h;
    const int wt = bh * 9 + qt;
    const int tid = threadIdx.x;
    const int lane = tid & 63;
    const int wv = tid >> 6;           // 0..3 = row quarter (divergent form)
    const int wvu = __builtin_amdgcn_readfirstlane(wv);  // provably uniform
    const int kc = gg;                 // chunk column group (3 columns)

    // ---- stage relh: 95 rows x 8 floats = 190 float4 ----
    for (int t = tid; t < 190; t += 256) lds[t] = ((const float4*)relh)[t];

    // ---- this lane's four queries (packed fp32 pairs) ----
    v2f Q0[4], Q1[4], Q2[4], Q3[4];
    int xq[4], ro[4];
#pragma unroll
    for (int j = 0; j < 4; ++j) {
        const int n = qt * 256 + j * 64 + lane;
        const int y = n / WW;
        xq[j] = n - y * WW;
        ro[j] = (47 - y) * 8;          // relh row offset (floats), + y2*8 in loop
        const float* qp = in + ((size_t)(b * NQ + n) * 192 + h * 8);
        float4 a = *(const float4*)qp, bb = *(const float4*)(qp + 4);
        Q0[j] = (v2f){a.x * SCL, a.y * SCL};
        Q1[j] = (v2f){a.z * SCL, a.w * SCL};
        Q2[j] = (v2f){bb.x * SCL, bb.y * SCL};
        Q3[j] = (v2f){bb.z * SCL, bb.w * SCL};
    }

    // ---- qw per (query, chunk column) from global relw; SHIFT folded in ----
    float qw[4][3];
#pragma unroll
    for (int j = 0; j < 4; ++j)
#pragma unroll
        for (int c = 0; c < 3; ++c) {
            const float* rw = relw + (kc * 3 + c - xq[j] + 47) * 8;
            float4 ta = *(const float4*)rw, tb = *(const float4*)(rw + 4);
            v2f s = v2fma(Q0[j], (v2f){ta.x, ta.y},
                    v2fma(Q1[j], (v2f){ta.z, ta.w},
                    v2fma(Q2[j], (v2f){tb.x, tb.y},
                          Q3[j] * (v2f){tb.z, tb.w})));
            qw[j][c] = s.x + s.y - SHIFT;
        }

    __syncthreads();   // staged relh visible to all 4 waves

    float l[4] = {0, 0, 0, 0};
    v2f A0[4], A1[4], A2[4], A3[4];
#pragma unroll
    for (int j = 0; j < 4; ++j) {
        A0[j] = (v2f){0.f, 0.f}; A1[j] = (v2f){0.f, 0.f};
        A2[j] = (v2f){0.f, 0.f}; A3[j] = (v2f){0.f, 0.f};
    }
    const float* relh_lds = (const float*)lds;

#pragma unroll 1
    for (int R = 0; R < 3; ++R) {
#pragma unroll 2
        for (int row = 0; row < 4; ++row) {
            const int y2 = wvu * 12 + R * 4 + row;      // uniform chain
            // ---- qh inline: 2 near-broadcast LDS reads + 4 pk_fma per j ----
            float qhv[4];
#pragma unroll
            for (int j = 0; j < 4; ++j) {
                const float* rp = relh_lds + ro[j] + y2 * 8;
                const float4 ra = *(const float4*)rp;
                const float4 rb = *(const float4*)(rp + 4);
                v2f s = v2fma(Q0[j], (v2f){ra.x, ra.y},
                        v2fma(Q1[j], (v2f){ra.z, ra.w},
                        v2fma(Q2[j], (v2f){rb.x, rb.y},
                              Q3[j] * (v2f){rb.z, rb.w})));
                qhv[j] = s.x + s.y;
            }
            // ---- t2 = qh + qw per (j,c): becomes the fma-chain init ----
            float t2[4][3];
#pragma unroll
            for (int j = 0; j < 4; ++j)
#pragma unroll
                for (int c = 0; c < 3; ++c) t2[j][c] = qhv[j] + qw[j][c];
            // ---- K/V: wave-uniform 32B chunks straight from global ----
            const float* kvrow = in + (size_t)(b * NQ + y2 * 48 + kc * 3) * 192
                                    + h * 8;
#pragma unroll
            for (int c = 0; c < 3; ++c) {
                const float* kvb = kvrow + c * 192;
                const float4 k0 = *(const float4*)(kvb + 64);
                const float4 k1 = *(const float4*)(kvb + 68);
                const float4 v0 = *(const float4*)(kvb + 128);
                const float4 v1 = *(const float4*)(kvb + 132);
                const v2f K0 = {k0.x, k0.y}, K1 = {k0.z, k0.w};
                const v2f K2 = {k1.x, k1.y}, K3 = {k1.z, k1.w};
                const v2f V0 = {v0.x, v0.y}, V1 = {v0.z, v0.w};
                const v2f V2 = {v1.x, v1.y}, V3 = {v1.z, v1.w};
#pragma unroll
                for (int j = 0; j < 4; ++j) {
                    v2f d = v2fma(Q0[j], K0,
                            v2fma(Q1[j], K1,
                            v2fma(Q2[j], K2,
                            v2fma(Q3[j], K3, (v2f){t2[j][c], 0.f}))));
                    const float p = __builtin_amdgcn_exp2f(d.x + d.y);
                    l[j] += p;
                    const v2f pp = {p, p};
                    A0[j] = v2fma(pp, V0, A0[j]);
                    A1[j] = v2fma(pp, V1, A1[j]);
                    A2[j] = v2fma(pp, V2, A2[j]);
                    A3[j] = v2fma(pp, V3, A3[j]);
                }
            }
        }
    }

    // ---- two-phase in-block merge (LDS: 2 regions of 2304 floats) ----
    __syncthreads();   // all waves done reading relh; safe to overwrite
    float* mr = (float*)(lds + (wv >> 1) * 576);   // region per wave-pair
    if ((wv & 1) == 0) {
#pragma unroll
        for (int j = 0; j < 4; ++j) {
            const int q = j * 64 + lane;
            mr[q] = l[j];
            mr[1 * 256 + q] = A0[j].x; mr[2 * 256 + q] = A0[j].y;
            mr[3 * 256 + q] = A1[j].x; mr[4 * 256 + q] = A1[j].y;
            mr[5 * 256 + q] = A2[j].x; mr[6 * 256 + q] = A2[j].y;
            mr[7 * 256 + q] = A3[j].x; mr[8 * 256 + q] = A3[j].y;
        }
    }
    __syncthreads();
    if ((wv & 1) == 1) {
#pragma unroll
        for (int j = 0; j < 4; ++j) {
            const int q = j * 64 + lane;
            mr[q] += l[j];
            mr[1 * 256 + q] += A0[j].x; mr[2 * 256 + q] += A0[j].y;
            mr[3 * 256 + q] += A1[j].x; mr[4 * 256 + q] += A1[j].y;
            mr[5 * 256 + q] += A2[j].x; mr[6 * 256 + q] += A2[j].y;
            mr[7 * 256 + q] += A3[j].x; mr[8 * 256 + q] += A3[j].y;
        }
    }
    __syncthreads();

    // ---- single atomic layer per block (XCD-local ACC lines) ----
    const float* r0 = (const float*)lds;
    const float* r1 = (const float*)(lds + 576);
    float* ab = ACC + (size_t)wt * 2304;
    for (int idx = tid; idx < 2304; idx += 256)
        atomicAdd(ab + idx, r0[idx] + r1[idx]);
}

// ---------------------------------------------------------------------------
// normalize: read ACC, divide by l, write out[b][n][h*8+j]
// Separate dispatch (R25 lesson: the kernel boundary IS the coherence
// mechanism for the cross-block ACC consume).
// ---------------------------------------------------------------------------
__global__ __launch_bounds__(64) void norm_kernel(const float* __restrict__ ACC,
                                                  float* __restrict__ out) {
    const int bxx = blockIdx.x;
    const int wt = bxx >> 2;
    const int q = (bxx & 3) * 64 + threadIdx.x;
    const float* ab = ACC + (size_t)wt * 2304;
    const float inv = 1.0f / ab[q];
    float s[8];
#pragma unroll
    for (int e = 0; e < 8; ++e) s[e] = ab[(1 + e) * 256 + q] * inv;
    const int bh = wt / 9;
    const int qtl = wt - bh * 9;
    const int n = qtl * 256 + q;
    const int b = bh >> 3, h = bh & 7;
    float* op = out + ((size_t)(b * NQ + n) * 64 + h * 8);
    ((float4*)op)[0] = make_float4(s[0], s[1], s[2], s[3]);
    ((float4*)op)[1] = make_float4(s[4], s[5], s[6], s[7]);
}

extern "C" void kernel_launch(void* const* d_in, const int* in_sizes, int n_in,
                              void* d_out, int out_size, void* d_ws, size_t ws_size,
                              hipStream_t stream) {
    const float* in   = (const float*)d_in[0];
    const float* relw = (const float*)d_in[1];
    const float* relh = (const float*)d_in[2];
    float* ACC = (float*)d_ws;                 // 1.33 MB
    float* out = (float*)d_out;

    hipMemsetAsync(ACC, 0, ACCF * sizeof(float), stream);
    attn_kernel<<<16 * NWT, 256, 0, stream>>>(in, relw, relh, ACC);
    norm_kernel<<<4 * NWT, 64, 0, stream>>>(ACC, out);
}

// Round 10
// 112.399 us; speedup vs baseline: 1.2133x; 1.2133x over previous
//
#include <hip/hip_runtime.h>
#include <stdint.h>

#define WW 48
#define NQ 2304             // 48*48
#define NWT 144             // (bh, qt) tiles of 256 queries
#define SCL 0.51011868f     // 8^-0.5 * log2(e)  (folded so softmax = exp2)
#define SHIFT 17.312340491f // 12 * log2(e)      (fixed-shift softmax)
#define ACCF (NWT * 2304)   // 331776 floats: ACC[wt][9][256]
// ws layout (floats): [0,ACCF) ACC

typedef float v2f __attribute__((ext_vector_type(2)));

__device__ __forceinline__ v2f v2fma(v2f a, v2f b, v2f c) {
    return __builtin_elementwise_fma(a, b, c);   // -> v_pk_fma_f32
}

// ---------------------------------------------------------------------------
// attn: R29 = R27 (best: 59.1us attn, total 109.5us) + qh hoisted to a
// per-R-segment batch to decouple the DS and SMEM lgkmcnt streams.
// R28 lesson: j=4 variant broke s_load promotion (SGPR 96->48) and
// regressed to 92us — SGPR_Count ~96-112 is the scalarization CANARY; any
// restructure must re-verify it. REVERTED to the j=2 R27 body.
// R27 evidence: FETCH 7MB (XCD-keying works), VALUBusy ~65% = ~38us VALU
// occupancy; residual ~21us stall = lgkmcnt waits. DS and SMEM share
// lgkmcnt on gfx9: the old loop interleaved 4 ds_read_b128 (relh qh) with
// 12 K/V s_loads PER ROW -> coarse lgkmcnt(0) drains every row. R29: 
// compute qh[2][4] at segment top (16 ds_reads batched, 8 VGPR, statically
// indexed via unrolled loops); the 12 (row,c) iterations that follow are
// LDS-FREE -> pure SMEM stream, fine-grained waits, pipelinable across the
// unroll-2 row pairs. Per-logit VALU unchanged.
// __launch_bounds__(256,4): R27 measured VGPR 36; +8 qh + temps stays well
// under the 64 cap. Occupancy itself is an impotent lever (VALUBusy flat
// across occ 17->58%, R21/R24/R27) — this round is about wait granularity.
// R20: no VGPR K/V double-buffering (spills). R25: no in-launch finish
// counters (norm stays a separate dispatch = the coherence boundary).
// Diagnostics: SGPR ~96-112 (canary), WRITE flat 20.7MB (spill tripwire).
// logit = q.k + q.rel_w[x2-x+47] + q.rel_h[y2-y+47]; p = exp2(logit-SHIFT)
// ---------------------------------------------------------------------------
__global__ __launch_bounds__(256, 4) void attn_kernel(const float* __restrict__ in,
                                                      const float* __restrict__ relw,
                                                      const float* __restrict__ relh,
                                                      float* __restrict__ ACC) {
    __shared__ float4 lds[576];        // 9216 B: [0,190) relh during loop;
                                       // [0,576) 2 merge regions after loop

    const int bx = blockIdx.x;
    // ---- XCD-keyed decode: bx%8 = h ----
    const int h = bx & 7;
    const int rest = bx >> 3;          // 0..575
    const int b = rest & 1;
    const int qg = rest >> 1;          // 0..287 = gs*9 + qt
    const int qt = qg % 9;
    const int gs = qg / 9;             // 0..31 = gg*2 + sub
    const int gg = gs >> 1;            // 0..15 (one 3-column chunk each)
    const int sub = gs & 1;            // 0..1  (which 128-query half-tile)
    const int bh = b * 8 + h;
    const int wt = bh * 9 + qt;
    const int tid = threadIdx.x;
    const int lane = tid & 63;
    const int wv = tid >> 6;           // 0..3 = row quarter (divergent form)
    const int wvu = __builtin_amdgcn_readfirstlane(wv);  // provably uniform
    const int kc = gg;                 // chunk column group (3 columns)

    // ---- stage relh: 95 rows x 8 floats = 190 float4 ----
    for (int t = tid; t < 190; t += 256) lds[t] = ((const float4*)relh)[t];

    // ---- this lane's two queries (packed fp32 pairs) ----
    v2f Q0[2], Q1[2], Q2[2], Q3[2];
    int xq[2], ro[2];
#pragma unroll
    for (int j = 0; j < 2; ++j) {
        const int n = qt * 256 + sub * 128 + j * 64 + lane;
        const int y = n / WW;
        xq[j] = n - y * WW;
        ro[j] = (47 - y) * 8;          // relh row offset (floats), + y2*8 in loop
        const float* qp = in + ((size_t)(b * NQ + n) * 192 + h * 8);
        float4 a = *(const float4*)qp, bb = *(const float4*)(qp + 4);
        Q0[j] = (v2f){a.x * SCL, a.y * SCL};
        Q1[j] = (v2f){a.z * SCL, a.w * SCL};
        Q2[j] = (v2f){bb.x * SCL, bb.y * SCL};
        Q3[j] = (v2f){bb.z * SCL, bb.w * SCL};
    }

    // ---- qw per (query, chunk column) from global relw; SHIFT folded in ----
    float qw[2][3];
#pragma unroll
    for (int j = 0; j < 2; ++j)
#pragma unroll
        for (int c = 0; c < 3; ++c) {
            const float* rw = relw + (kc * 3 + c - xq[j] + 47) * 8;
            float4 ta = *(const float4*)rw, tb = *(const float4*)(rw + 4);
            v2f s = v2fma(Q0[j], (v2f){ta.x, ta.y},
                    v2fma(Q1[j], (v2f){ta.z, ta.w},
                    v2fma(Q2[j], (v2f){tb.x, tb.y},
                          Q3[j] * (v2f){tb.z, tb.w})));
            qw[j][c] = s.x + s.y - SHIFT;
        }

    __syncthreads();   // staged relh visible to all 4 waves

    float l[2] = {0, 0};
    v2f A0[2], A1[2], A2[2], A3[2];
#pragma unroll
    for (int j = 0; j < 2; ++j) {
        A0[j] = (v2f){0.f, 0.f}; A1[j] = (v2f){0.f, 0.f};
        A2[j] = (v2f){0.f, 0.f}; A3[j] = (v2f){0.f, 0.f};
    }
    const float* relh_lds = (const float*)lds;

#pragma unroll 1
    for (int R = 0; R < 3; ++R) {
        // ---- qh batch for this segment's 4 rows: 16 ds_reads, then the
        //      row loop below is LDS-free (pure SMEM lgkmcnt stream) ----
        float qh[2][4];
#pragma unroll
        for (int row = 0; row < 4; ++row) {
            const int y2 = wvu * 12 + R * 4 + row;
#pragma unroll
            for (int j = 0; j < 2; ++j) {
                const float* rp = relh_lds + ro[j] + y2 * 8;
                const float4 ra = *(const float4*)rp;
                const float4 rb = *(const float4*)(rp + 4);
                v2f s = v2fma(Q0[j], (v2f){ra.x, ra.y},
                        v2fma(Q1[j], (v2f){ra.z, ra.w},
                        v2fma(Q2[j], (v2f){rb.x, rb.y},
                              Q3[j] * (v2f){rb.z, rb.w})));
                qh[j][row] = s.x + s.y;
            }
        }

#pragma unroll 2
        for (int row = 0; row < 4; ++row) {
            const int y2 = wvu * 12 + R * 4 + row;      // uniform chain
            // ---- t2 = qh + qw per (j,c): becomes the fma-chain init ----
            float t2[2][3];
#pragma unroll
            for (int j = 0; j < 2; ++j)
#pragma unroll
                for (int c = 0; c < 3; ++c) t2[j][c] = qh[j][row] + qw[j][c];
            // ---- K/V: wave-uniform 32B chunks straight from global ----
            const float* kvrow = in + (size_t)(b * NQ + y2 * 48 + kc * 3) * 192
                                    + h * 8;
#pragma unroll
            for (int c = 0; c < 3; ++c) {
                const float* kvb = kvrow + c * 192;
                const float4 k0 = *(const float4*)(kvb + 64);
                const float4 k1 = *(const float4*)(kvb + 68);
                const float4 v0 = *(const float4*)(kvb + 128);
                const float4 v1 = *(const float4*)(kvb + 132);
                const v2f K0 = {k0.x, k0.y}, K1 = {k0.z, k0.w};
                const v2f K2 = {k1.x, k1.y}, K3 = {k1.z, k1.w};
                const v2f V0 = {v0.x, v0.y}, V1 = {v0.z, v0.w};
                const v2f V2 = {v1.x, v1.y}, V3 = {v1.z, v1.w};
#pragma unroll
                for (int j = 0; j < 2; ++j) {
                    v2f d = v2fma(Q0[j], K0,
                            v2fma(Q1[j], K1,
                            v2fma(Q2[j], K2,
                            v2fma(Q3[j], K3, (v2f){t2[j][c], 0.f}))));
                    const float p = __builtin_amdgcn_exp2f(d.x + d.y);
                    l[j] += p;
                    const v2f pp = {p, p};
                    A0[j] = v2fma(pp, V0, A0[j]);
                    A1[j] = v2fma(pp, V1, A1[j]);
                    A2[j] = v2fma(pp, V2, A2[j]);
                    A3[j] = v2fma(pp, V3, A3[j]);
                }
            }
        }
    }

    // ---- two-phase in-block merge (LDS: 2 regions of 1152 floats) ----
    // region layout: [e][128], e=0 -> l, e=1..8 -> A components
    __syncthreads();   // all waves done reading relh; safe to overwrite
    float* mr = (float*)(lds + (wv >> 1) * 288);   // region per wave-pair
    if ((wv & 1) == 0) {
#pragma unroll
        for (int j = 0; j < 2; ++j) {
            const int q = j * 64 + lane;
            mr[q] = l[j];
            mr[1 * 128 + q] = A0[j].x; mr[2 * 128 + q] = A0[j].y;
            mr[3 * 128 + q] = A1[j].x; mr[4 * 128 + q] = A1[j].y;
            mr[5 * 128 + q] = A2[j].x; mr[6 * 128 + q] = A2[j].y;
            mr[7 * 128 + q] = A3[j].x; mr[8 * 128 + q] = A3[j].y;
        }
    }
    __syncthreads();
    if ((wv & 1) == 1) {
#pragma unroll
        for (int j = 0; j < 2; ++j) {
            const int q = j * 64 + lane;
            mr[q] += l[j];
            mr[1 * 128 + q] += A0[j].x; mr[2 * 128 + q] += A0[j].y;
            mr[3 * 128 + q] += A1[j].x; mr[4 * 128 + q] += A1[j].y;
            mr[5 * 128 + q] += A2[j].x; mr[6 * 128 + q] += A2[j].y;
            mr[7 * 128 + q] += A3[j].x; mr[8 * 128 + q] += A3[j].y;
        }
    }
    __syncthreads();

    // ---- single atomic layer per block (XCD-local ACC lines) ----
    const float* r0 = (const float*)lds;
    const float* r1 = (const float*)(lds + 288);
    float* ab = ACC + (size_t)wt * 2304 + sub * 128;
    for (int idx = tid; idx < 1152; idx += 256) {
        const int e = idx >> 7, qq = idx & 127;
        atomicAdd(ab + e * 256 + qq, r0[idx] + r1[idx]);
    }
}

// ---------------------------------------------------------------------------
// normalize: read ACC, divide by l, write out[b][n][h*8+j]
// Separate dispatch (R25 lesson: the kernel boundary IS the coherence
// mechanism for the cross-block ACC consume).
// ---------------------------------------------------------------------------
__global__ __launch_bounds__(64) void norm_kernel(const float* __restrict__ ACC,
                                                  float* __restrict__ out) {
    const int bxx = blockIdx.x;
    const int wt = bxx >> 2;
    const int q = (bxx & 3) * 64 + threadIdx.x;
    const float* ab = ACC + (size_t)wt * 2304;
    const float inv = 1.0f / ab[q];
    float s[8];
#pragma unroll
    for (int e = 0; e < 8; ++e) s[e] = ab[(1 + e) * 256 + q] * inv;
    const int bh = wt / 9;
    const int qtl = wt - bh * 9;
    const int n = qtl * 256 + q;
    const int b = bh >> 3, h = bh & 7;
    float* op = out + ((size_t)(b * NQ + n) * 64 + h * 8);
    ((float4*)op)[0] = make_float4(s[0], s[1], s[2], s[3]);
    ((float4*)op)[1] = make_float4(s[4], s[5], s[6], s[7]);
}

extern "C" void kernel_launch(void* const* d_in, const int* in_sizes, int n_in,
                              void* d_out, int out_size, void* d_ws, size_t ws_size,
                              hipStream_t stream) {
    const float* in   = (const float*)d_in[0];
    const float* relw = (const float*)d_in[1];
    const float* relh = (const float*)d_in[2];
    float* ACC = (float*)d_ws;                 // 1.33 MB
    float* out = (float*)d_out;

    hipMemsetAsync(ACC, 0, ACCF * sizeof(float), stream);
    attn_kernel<<<32 * NWT, 256, 0, stream>>>(in, relw, relh, ACC);
    norm_kernel<<<4 * NWT, 64, 0, stream>>>(ACC, out);
}